// Round 9
// baseline (1500.044 us; speedup 1.0000x reference)
//
#include <hip/hip_runtime.h>
#include <hip/hip_cooperative_groups.h>
#include <stdint.h>

namespace cg = cooperative_groups;

#define N_NODES 50000
#define N_EDGES 800000
#define HID 128
#define NCLS 10
#define NGRAPH 64
#define CAP 64   // bucket capacity; deg ~ Poisson(16), P(max>64) < 1e-20
#define MEGA_GRID 1536
#define MEGA_THREADS (MEGA_GRID * 256)
#define NTILES 3125

typedef unsigned short ushort_t;
typedef __attribute__((ext_vector_type(8))) short bf16x8;
typedef __attribute__((ext_vector_type(4))) float f32x4;
typedef __attribute__((ext_vector_type(4))) _Float16 f16x4;
typedef __attribute__((ext_vector_type(8))) _Float16 f16x8;

__device__ __forceinline__ ushort_t f2bf(float f) {
    union { float f; unsigned int i; } v; v.f = f;
    unsigned int u = v.i;
    return (ushort_t)((u + 0x7FFFu + ((u >> 16) & 1u)) >> 16);
}
__device__ __forceinline__ float bf2f(ushort_t u) {
    union { unsigned int i; float f; } v; v.i = ((unsigned int)u) << 16; return v.f;
}
// UNSIGNED extraction — (p>>16) on signed int sign-extends for ids>=32768
__device__ __forceinline__ int exhi(int p) { return (p >> 16) & 0xffff; }
__device__ __forceinline__ int exlo(int p) { return p & 0xffff; }
__device__ __forceinline__ void add4h(float4& a, f16x4 v) {
    a.x += (float)v[0];
    a.y += (float)v[1];
    a.z += (float)v[2];
    a.w += (float)v[3];
}

// ---------- shared device bodies (used by both mega and fallback) ----------

__device__ __forceinline__ void wsplit_item(int gid,
        const float* __restrict__ W0, const float* __restrict__ W1,
        const float* __restrict__ W2, ushort_t* Whi, ushort_t* Wlo) {
    int l = gid / (32 * 512);
    int rem = gid - l * 32 * 512;
    int tile = rem >> 9;
    int p = rem & 511;
    int lane = p >> 3, j = p & 7;
    int kk = tile >> 3, c = tile & 7;
    int k = 32 * kk + (lane >> 4) * 8 + j;
    int n = 16 * c + (lane & 15);
    const float* W = (l == 0) ? W0 : (l == 1) ? W1 : W2;
    float x = W[k * 128 + n];
    ushort_t hi = f2bf(x);
    ushort_t lo = f2bf(x - bf2f(hi));
    Whi[l * 16384 + rem] = hi;
    Wlo[l * 16384 + rem] = lo;
}

__device__ __forceinline__ void fill8(int base, const int* __restrict__ src,
                                      const int* __restrict__ dst,
                                      int* cnt, ushort_t* csr16) {
    // 800000 % 8 == 0: base+7 < N_EDGES always for base = gtid*8 < N_EDGES
    int4 da = *(const int4*)(dst + base);
    int4 db = *(const int4*)(dst + base + 4);
    int4 sa = *(const int4*)(src + base);
    int4 sb = *(const int4*)(src + base + 4);
    int p0 = atomicAdd(&cnt[da.x], 1);
    int p1 = atomicAdd(&cnt[da.y], 1);
    int p2 = atomicAdd(&cnt[da.z], 1);
    int p3 = atomicAdd(&cnt[da.w], 1);
    int p4 = atomicAdd(&cnt[db.x], 1);
    int p5 = atomicAdd(&cnt[db.y], 1);
    int p6 = atomicAdd(&cnt[db.z], 1);
    int p7 = atomicAdd(&cnt[db.w], 1);
    if (p0 < CAP) csr16[da.x * CAP + p0] = (ushort_t)sa.x;
    if (p1 < CAP) csr16[da.y * CAP + p1] = (ushort_t)sa.y;
    if (p2 < CAP) csr16[da.z * CAP + p2] = (ushort_t)sa.z;
    if (p3 < CAP) csr16[da.w * CAP + p3] = (ushort_t)sa.w;
    if (p4 < CAP) csr16[db.x * CAP + p4] = (ushort_t)sb.x;
    if (p5 < CAP) csr16[db.y * CAP + p5] = (ushort_t)sb.y;
    if (p6 < CAP) csr16[db.z * CAP + p6] = (ushort_t)sb.z;
    if (p7 < CAP) csr16[db.w * CAP + p7] = (ushort_t)sb.w;
}

__device__ __forceinline__ void cvt_item(int gid, const float* __restrict__ x,
                                         const int* __restrict__ cnt,
                                         _Float16* __restrict__ X16) {
    int i = gid >> 4, seg = gid & 15;             // seg: 8-feature octet
    float isd = rsqrtf((float)cnt[i] + 1.0f);
    const f32x4* px = (const f32x4*)(x + (size_t)i * HID + seg * 8);
    f32x4 a = px[0], b = px[1];
    f16x8 o;
    o[0] = (_Float16)(isd * a.x); o[1] = (_Float16)(isd * a.y);
    o[2] = (_Float16)(isd * a.z); o[3] = (_Float16)(isd * a.w);
    o[4] = (_Float16)(isd * b.x); o[5] = (_Float16)(isd * b.y);
    o[6] = (_Float16)(isd * b.z); o[7] = (_Float16)(isd * b.w);
    *(f16x8*)(X16 + (size_t)i * HID + seg * 8) = o;
}

// round-7-verified fused layer body for ONE tile (16 nodes): gather + MFMA + epilogue
__device__ __forceinline__ void layer_tile(int tile, int t,
        const _Float16* __restrict__ In, const ushort_t* __restrict__ csr16,
        const int* __restrict__ cnt, const ushort_t* __restrict__ Whi,
        const ushort_t* __restrict__ Wlo, const float* __restrict__ bias,
        int scale_out, int pool, const int* __restrict__ batch,
        float* sums, float* maxs, _Float16* __restrict__ Out,
        float (*T)[132], int* sg) {
    int wv = t >> 6, lane = t & 63;
    int hl = lane & 31, q = lane >> 5;   // half-lane, half-index
    if (pool && t < 16) sg[t] = batch[tile * 16 + t];

    // ---- gather phase: wave wv aggregates nodes (tile*16 + wv*4 + r)
    for (int r = 0; r < 4; r++) {
        int i = tile * 16 + wv * 4 + r;
        int ci = cnt[i];
        int m = min(ci, CAP);
        float isdi = rsqrtf((float)ci + 1.0f);
        int packed = ((const int*)(csr16 + (size_t)i * CAP))[hl];
        float4 a0 = make_float4(0.f, 0.f, 0.f, 0.f);
        float4 a1 = a0, a2 = a0, a3 = a0;
        if (q == 0) {
            f16x4 sv = *(const f16x4*)(In + (size_t)i * HID + hl * 4);
            add4h(a0, sv);                         // self term (pre-scaled table)
        }
        int e = 0;
        for (; e + 15 < m; e += 16) {              // 8 gathers in flight per lane
            int k0 = e >> 1;
            int p0 = __shfl(packed, k0);
            int p1 = __shfl(packed, k0 + 1);
            int p2 = __shfl(packed, k0 + 2);
            int p3 = __shfl(packed, k0 + 3);
            int p4 = __shfl(packed, k0 + 4);
            int p5 = __shfl(packed, k0 + 5);
            int p6 = __shfl(packed, k0 + 6);
            int p7 = __shfl(packed, k0 + 7);
            int s0 = q ? exhi(p0) : exlo(p0);
            int s1 = q ? exhi(p1) : exlo(p1);
            int s2 = q ? exhi(p2) : exlo(p2);
            int s3 = q ? exhi(p3) : exlo(p3);
            int s4 = q ? exhi(p4) : exlo(p4);
            int s5 = q ? exhi(p5) : exlo(p5);
            int s6 = q ? exhi(p6) : exlo(p6);
            int s7 = q ? exhi(p7) : exlo(p7);
            f16x4 v0 = *(const f16x4*)(In + (size_t)s0 * HID + hl * 4);
            f16x4 v1 = *(const f16x4*)(In + (size_t)s1 * HID + hl * 4);
            f16x4 v2 = *(const f16x4*)(In + (size_t)s2 * HID + hl * 4);
            f16x4 v3 = *(const f16x4*)(In + (size_t)s3 * HID + hl * 4);
            f16x4 v4 = *(const f16x4*)(In + (size_t)s4 * HID + hl * 4);
            f16x4 v5 = *(const f16x4*)(In + (size_t)s5 * HID + hl * 4);
            f16x4 v6 = *(const f16x4*)(In + (size_t)s6 * HID + hl * 4);
            f16x4 v7 = *(const f16x4*)(In + (size_t)s7 * HID + hl * 4);
            add4h(a0, v0); add4h(a1, v1); add4h(a2, v2); add4h(a3, v3);
            add4h(a0, v4); add4h(a1, v5); add4h(a2, v6); add4h(a3, v7);
        }
        for (; e + 7 < m; e += 8) {
            int k0 = e >> 1;
            int p0 = __shfl(packed, k0);
            int p1 = __shfl(packed, k0 + 1);
            int p2 = __shfl(packed, k0 + 2);
            int p3 = __shfl(packed, k0 + 3);
            int s0 = q ? exhi(p0) : exlo(p0);
            int s1 = q ? exhi(p1) : exlo(p1);
            int s2 = q ? exhi(p2) : exlo(p2);
            int s3 = q ? exhi(p3) : exlo(p3);
            f16x4 v0 = *(const f16x4*)(In + (size_t)s0 * HID + hl * 4);
            f16x4 v1 = *(const f16x4*)(In + (size_t)s1 * HID + hl * 4);
            f16x4 v2 = *(const f16x4*)(In + (size_t)s2 * HID + hl * 4);
            f16x4 v3 = *(const f16x4*)(In + (size_t)s3 * HID + hl * 4);
            add4h(a0, v0); add4h(a1, v1); add4h(a2, v2); add4h(a3, v3);
        }
        for (; e + 1 < m; e += 2) {
            int p = __shfl(packed, e >> 1);
            int s0 = q ? exhi(p) : exlo(p);
            f16x4 v0 = *(const f16x4*)(In + (size_t)s0 * HID + hl * 4);
            add4h(a0, v0);
        }
        if (e < m && q == 0) {
            int p = __shfl(packed, e >> 1);
            int s0 = exlo(p);
            f16x4 v0 = *(const f16x4*)(In + (size_t)s0 * HID + hl * 4);
            add4h(a0, v0);
        }
        float4 s4v;
        s4v.x = (a0.x + a1.x) + (a2.x + a3.x);
        s4v.y = (a0.y + a1.y) + (a2.y + a3.y);
        s4v.z = (a0.z + a1.z) + (a2.z + a3.z);
        s4v.w = (a0.w + a1.w) + (a2.w + a3.w);
        s4v.x += __shfl_xor(s4v.x, 32);
        s4v.y += __shfl_xor(s4v.y, 32);
        s4v.z += __shfl_xor(s4v.z, 32);
        s4v.w += __shfl_xor(s4v.w, 32);
        if (q == 0) {
            float4 o;
            o.x = isdi * s4v.x; o.y = isdi * s4v.y;
            o.z = isdi * s4v.z; o.w = isdi * s4v.w;
            *(float4*)&T[wv * 4 + r][hl * 4] = o;
        }
    }
    __syncthreads();

    // ---- MFMA phase: wave wv -> cols [wv*32, wv*32+32)
    int mrow = lane & 15, qq = lane >> 4;
    f32x4 acc[2];
    acc[0] = (f32x4){0.f, 0.f, 0.f, 0.f};
    acc[1] = (f32x4){0.f, 0.f, 0.f, 0.f};
#pragma unroll
    for (int kk = 0; kk < 4; kk++) {
        const float* tp = &T[mrow][kk * 32 + qq * 8];
        float4 p0 = *(const float4*)tp;
        float4 p1 = *(const float4*)(tp + 4);
        float av[8] = {p0.x, p0.y, p0.z, p0.w, p1.x, p1.y, p1.z, p1.w};
        bf16x8 ahi, alo;
#pragma unroll
        for (int j = 0; j < 8; j++) {
            ushort_t hbits = f2bf(av[j]);
            ahi[j] = (short)hbits;
            alo[j] = (short)f2bf(av[j] - bf2f(hbits));
        }
#pragma unroll
        for (int cl = 0; cl < 2; cl++) {
            int c = wv * 2 + cl;
            const bf16x8 bhi = *(const bf16x8*)(Whi + (((kk * 8 + c) * 64 + lane) << 3));
            const bf16x8 blo = *(const bf16x8*)(Wlo + (((kk * 8 + c) * 64 + lane) << 3));
            acc[cl] = __builtin_amdgcn_mfma_f32_16x16x32_bf16(ahi, bhi, acc[cl], 0, 0, 0);
            acc[cl] = __builtin_amdgcn_mfma_f32_16x16x32_bf16(alo, bhi, acc[cl], 0, 0, 0);
            acc[cl] = __builtin_amdgcn_mfma_f32_16x16x32_bf16(ahi, blo, acc[cl], 0, 0, 0);
        }
    }
    // epilogue: C/D col = mrow, row = qq*4+rr
    int rb = tile * 16 + qq * 4;
    if (!pool) {
        float osc[4];
#pragma unroll
        for (int rr = 0; rr < 4; rr++)
            osc[rr] = scale_out ? rsqrtf((float)cnt[rb + rr] + 1.0f) : 1.0f;
#pragma unroll
        for (int cl = 0; cl < 2; cl++) {
            int col = (wv * 2 + cl) * 16 + mrow;
            float bcol = bias[col];
#pragma unroll
            for (int rr = 0; rr < 4; rr++) {
                float val = fmaxf(acc[cl][rr] + bcol, 0.f);
                Out[(size_t)(rb + rr) * HID + col] = (_Float16)(val * osc[rr]);
            }
        }
    } else {
        __syncthreads();   // all waves done reading T
#pragma unroll
        for (int cl = 0; cl < 2; cl++) {
            int col = (wv * 2 + cl) * 16 + mrow;
            float bcol = bias[col];
#pragma unroll
            for (int rr = 0; rr < 4; rr++)
                T[qq * 4 + rr][col] = fmaxf(acc[cl][rr] + bcol, 0.f);
        }
        __syncthreads();
        int f = t & 127, half = t >> 7;   // half 0: sums, half 1: maxs
        int cur = sg[0];
        float s = 0.f, mx = 0.f;
        for (int r = 0; r < 16; r++) {
            int g = sg[r];
            if (g != cur) {
                if (half == 0) atomicAdd(&sums[cur * HID + f], s);
                else atomicMax((int*)&maxs[cur * HID + f], __float_as_int(mx));
                s = 0.f; mx = 0.f; cur = g;
            }
            float v = T[r][f];
            s += v;
            mx = fmaxf(mx, v);
        }
        if (half == 0) atomicAdd(&sums[cur * HID + f], s);
        else atomicMax((int*)&maxs[cur * HID + f], __float_as_int(mx));
    }
}

// layer phase: dynamic tile scheduling via global atomic counter
__device__ void layer_phase(int t,
        const _Float16* __restrict__ In, const ushort_t* __restrict__ csr16,
        const int* __restrict__ cnt, const ushort_t* __restrict__ Whi,
        const ushort_t* __restrict__ Wlo, const float* __restrict__ bias,
        int scale_out, int pool, const int* __restrict__ batch,
        float* sums, float* maxs, _Float16* __restrict__ Out,
        float (*T)[132], int* sg, int* tctr, int* stile) {
    for (;;) {
        __syncthreads();              // protects T reuse + stile
        if (t == 0) *stile = atomicAdd(tctr, 1);
        __syncthreads();
        int tile = *stile;
        if (tile >= NTILES) break;
        layer_tile(tile, t, In, csr16, cnt, Whi, Wlo, bias, scale_out, pool,
                   batch, sums, maxs, Out, T, sg);
    }
}

// ---------------- the cooperative mega-kernel ----------------
__global__ void __launch_bounds__(256, 6)
k_mega(const float* __restrict__ x, const int* __restrict__ src,
       const int* __restrict__ dst, const int* __restrict__ batch,
       const float* __restrict__ W0, const float* __restrict__ b0,
       const float* __restrict__ W1, const float* __restrict__ b1,
       const float* __restrict__ W2, const float* __restrict__ b2,
       const float* __restrict__ Wa, const float* __restrict__ ba,
       float* __restrict__ out,
       int* cnt, int* bound, int* counts, int* tctr,
       float* sums, float* maxs, ushort_t* Whi, ushort_t* Wlo, ushort_t* csr16,
       _Float16* X16, _Float16* hA, _Float16* hB) {
    cg::grid_group grid = cg::this_grid();
    __shared__ float T[16][132];
    __shared__ int sg[16];
    __shared__ int stile;
    __shared__ float fa[256];
    __shared__ float fred[4];
    int bid = blockIdx.x, t = threadIdx.x;
    int gtid = bid * 256 + t;

    // ---- phase 0: zero state + graph bounds + weight split
    if (gtid < N_NODES) cnt[gtid] = 0;
    if (gtid < NGRAPH * HID) { sums[gtid] = 0.f; maxs[gtid] = 0.f; }
    if (gtid < 8) tctr[gtid] = 0;
    if (gtid < NGRAPH + 1) {
        int g = gtid, lo = 0, hi = N_NODES;
        while (lo < hi) {
            int mid = (lo + hi) >> 1;
            if (batch[mid] < g) lo = mid + 1; else hi = mid;
        }
        bound[g] = lo;
    }
    if (gtid >= 65536 && gtid < 65536 + 49152)
        wsplit_item(gtid - 65536, W0, W1, W2, Whi, Wlo);
    grid.sync();

    // ---- phase 1: per-graph counts + bucket-CSR edge fill
    if (gtid < NGRAPH) counts[gtid] = bound[gtid + 1] - bound[gtid];
    if (gtid < N_EDGES / 8) fill8(gtid * 8, src, dst, cnt, csr16);
    grid.sync();

    // ---- phase 2: x -> fp16 pre-scaled table
    for (int g2 = gtid; g2 < N_NODES * 16; g2 += MEGA_THREADS)
        cvt_item(g2, x, cnt, X16);
    grid.sync();

    // ---- phases 3-5: GCN layers (layer 3 pools)
    layer_phase(t, X16, csr16, cnt, Whi, Wlo, b0, 1, 0,
                batch, sums, maxs, hA, T, sg, tctr + 0, &stile);
    grid.sync();
    layer_phase(t, hA, csr16, cnt, Whi + 16384, Wlo + 16384, b1, 1, 0,
                batch, sums, maxs, hB, T, sg, tctr + 1, &stile);
    grid.sync();
    layer_phase(t, hB, csr16, cnt, Whi + 32768, Wlo + 32768, b2, 0, 1,
                batch, sums, maxs, hA, T, sg, tctr + 2, &stile);
    grid.sync();

    // ---- phase 6: head (blocks 0..63, one graph each)
    if (bid < NGRAPH) {
        int g = bid;
        float denom = fmaxf((float)counts[g], 1.f);
        float val = (t < 128) ? (sums[g * HID + t] / denom)
                              : maxs[g * HID + (t - 128)];
        fa[t] = val;
        out[NGRAPH * NCLS + g * 256 + t] = val;
        __syncthreads();
        for (int c = 0; c < NCLS; c++) {
            float p = fa[t] * Wa[t * NCLS + c];
            for (int o = 32; o > 0; o >>= 1) p += __shfl_down(p, o);
            if ((t & 63) == 0) fred[t >> 6] = p;
            __syncthreads();
            if (t == 0)
                out[g * NCLS + c] = fred[0] + fred[1] + fred[2] + fred[3] + ba[c];
            __syncthreads();
        }
    }
}

// ================= fallback path: round-7 verified kernels =================

__global__ void k_prep(const int* __restrict__ src, const int* __restrict__ dst,
                       int* cnt, ushort_t* csr16,
                       const int* __restrict__ batch, int* bound, int* counts,
                       const float* __restrict__ W0, const float* __restrict__ W1,
                       const float* __restrict__ W2, ushort_t* Whi, ushort_t* Wlo) {
    int b = blockIdx.x, t = threadIdx.x;
    if (b < 391) {
        int base = (b * 256 + t) * 8;
        if (base + 7 < N_EDGES) fill8(base, src, dst, cnt, csr16);
    } else if (b == 391) {
        int g = t;
        if (g <= NGRAPH) {
            int lo = 0, hi = N_NODES;
            while (lo < hi) {
                int mid = (lo + hi) >> 1;
                if (batch[mid] < g) lo = mid + 1; else hi = mid;
            }
            bound[g] = lo;
        }
        __syncthreads();
        if (g < NGRAPH) counts[g] = bound[g + 1] - bound[g];
    } else {
        wsplit_item((b - 392) * 256 + t, W0, W1, W2, Whi, Wlo);
    }
}

__global__ void k_cvt(const float* __restrict__ x, const int* __restrict__ cnt,
                      _Float16* __restrict__ X16) {
    cvt_item(blockIdx.x * 256 + threadIdx.x, x, cnt, X16);
}

__global__ void k_layer(const _Float16* __restrict__ In,
                        const ushort_t* __restrict__ csr16, const int* __restrict__ cnt,
                        const ushort_t* __restrict__ Whi, const ushort_t* __restrict__ Wlo,
                        const float* __restrict__ bias, int scale_out,
                        int pool, const int* __restrict__ batch,
                        float* sums, float* maxs, _Float16* __restrict__ Out) {
    __shared__ float T[16][132];
    __shared__ int sg[16];
    layer_tile(blockIdx.x, threadIdx.x, In, csr16, cnt, Whi, Wlo, bias,
               scale_out, pool, batch, sums, maxs, Out, T, sg);
}

__global__ void k_final(const float* __restrict__ sums, const float* __restrict__ maxs,
                        const int* __restrict__ counts, const float* __restrict__ Wa,
                        const float* __restrict__ ba, float* __restrict__ out) {
    __shared__ float a[256];
    __shared__ float red[4];
    int g = blockIdx.x, t = threadIdx.x;
    float denom = fmaxf((float)counts[g], 1.f);
    float val = (t < 128) ? (sums[g * HID + t] / denom) : maxs[g * HID + (t - 128)];
    a[t] = val;
    out[NGRAPH * NCLS + g * 256 + t] = val;
    __syncthreads();
    for (int c = 0; c < NCLS; c++) {
        float p = a[t] * Wa[t * NCLS + c];
        for (int o = 32; o > 0; o >>= 1) p += __shfl_down(p, o);
        if ((t & 63) == 0) red[t >> 6] = p;
        __syncthreads();
        if (t == 0) {
            out[g * NCLS + c] = red[0] + red[1] + red[2] + red[3] + ba[c];
        }
        __syncthreads();
    }
}

extern "C" void kernel_launch(void* const* d_in, const int* in_sizes, int n_in,
                              void* d_out, int out_size, void* d_ws, size_t ws_size,
                              hipStream_t stream) {
    const float* x = (const float*)d_in[0];
    const int* ei = (const int*)d_in[1];
    const int* src = ei;
    const int* dst = ei + N_EDGES;
    const int* batch = (const int*)d_in[2];
    const float* W0 = (const float*)d_in[3];
    const float* b0 = (const float*)d_in[4];
    const float* W1 = (const float*)d_in[5];
    const float* b1 = (const float*)d_in[6];
    const float* W2 = (const float*)d_in[7];
    const float* b2 = (const float*)d_in[8];
    const float* Wa = (const float*)d_in[9];
    const float* ba = (const float*)d_in[10];
    float* out = (float*)d_out;

    char* ws = (char*)d_ws;
    int*       cnt    = (int*)(ws + 0);             // 50000 i32
    int*       bound  = (int*)(ws + 200192);        // 65 i32 (ends 200452)
    int*       tctr   = (int*)(ws + 200512);        // 8 i32 layer tile counters
    int*       counts = (int*)(ws + 200576);        // 64 i32
    float*     sums   = (float*)(ws + 200832);      // 8192 f32
    float*     maxs   = (float*)(ws + 233600);      // 8192 f32
    ushort_t*  Whi    = (ushort_t*)(ws + 266368);   // 3*16384 bf16
    ushort_t*  Wlo    = (ushort_t*)(ws + 364672);   // 3*16384 bf16
    ushort_t*  csr16  = (ushort_t*)(ws + 462976);   // 50000*64 u16 (6.4 MB)
    _Float16*  X16    = (_Float16*)(ws + 7462976);  // 50000x128 f16 (12.8 MB)
    _Float16*  hA     = (_Float16*)(ws + 20262976); // 50000x128 f16
    _Float16*  hB     = (_Float16*)(ws + 33062976); // 50000x128 f16
    // total 45,862,976 B

    void* args[] = {
        (void*)&x, (void*)&src, (void*)&dst, (void*)&batch,
        (void*)&W0, (void*)&b0, (void*)&W1, (void*)&b1,
        (void*)&W2, (void*)&b2, (void*)&Wa, (void*)&ba,
        (void*)&out, (void*)&cnt, (void*)&bound, (void*)&counts, (void*)&tctr,
        (void*)&sums, (void*)&maxs, (void*)&Whi, (void*)&Wlo, (void*)&csr16,
        (void*)&X16, (void*)&hA, (void*)&hB
    };
    hipError_t merr = hipLaunchCooperativeKernel(
        reinterpret_cast<void*>(k_mega), dim3(MEGA_GRID), dim3(256),
        args, 0, stream);
    if (merr != hipSuccess) {
        (void)hipGetLastError();   // clear sticky error; run verified path
        hipMemsetAsync(ws, 0, 266368, stream);
        k_prep<<<584, 256, 0, stream>>>(src, dst, cnt, csr16, batch, bound, counts,
                                        W0, W1, W2, Whi, Wlo);
        k_cvt<<<3125, 256, 0, stream>>>(x, cnt, X16);
        k_layer<<<3125, 256, 0, stream>>>(X16, csr16, cnt, Whi, Wlo, b0, 1,
                                          0, batch, sums, maxs, hA);
        k_layer<<<3125, 256, 0, stream>>>(hA, csr16, cnt, Whi + 16384, Wlo + 16384, b1, 1,
                                          0, batch, sums, maxs, hB);
        k_layer<<<3125, 256, 0, stream>>>(hB, csr16, cnt, Whi + 32768, Wlo + 32768, b2, 0,
                                          1, batch, sums, maxs, hA);
        k_final<<<NGRAPH, 256, 0, stream>>>(sums, maxs, counts, Wa, ba, out);
    }
}

// Round 10
// 514.194 us; speedup vs baseline: 2.9173x; 2.9173x over previous
//
#include <hip/hip_runtime.h>
#include <stdint.h>

#define N_NODES 50000
#define N_EDGES 800000
#define HID 128
#define NCLS 10
#define NGRAPH 64
#define CAP 64   // bucket capacity; deg ~ Poisson(16), P(max>64) < 1e-20
#define NTILES 3125

typedef unsigned short ushort_t;
typedef __attribute__((ext_vector_type(8))) short bf16x8;
typedef __attribute__((ext_vector_type(4))) float f32x4;
typedef __attribute__((ext_vector_type(4))) _Float16 f16x4;
typedef __attribute__((ext_vector_type(8))) _Float16 f16x8;

__device__ __forceinline__ ushort_t f2bf(float f) {
    union { float f; unsigned int i; } v; v.f = f;
    unsigned int u = v.i;
    return (ushort_t)((u + 0x7FFFu + ((u >> 16) & 1u)) >> 16);
}
__device__ __forceinline__ float bf2f(ushort_t u) {
    union { unsigned int i; float f; } v; v.i = ((unsigned int)u) << 16; return v.f;
}
// UNSIGNED extraction — (p>>16) on signed int sign-extends for ids>=32768
__device__ __forceinline__ int exhi(int p) { return (p >> 16) & 0xffff; }
__device__ __forceinline__ int exlo(int p) { return p & 0xffff; }
__device__ __forceinline__ void add4h(float4& a, f16x4 v) {
    a.x += (float)v[0];
    a.y += (float)v[1];
    a.z += (float)v[2];
    a.w += (float)v[3];
}
__device__ __forceinline__ void fmad4h(float4& a, float d, f16x4 v) {
    a.x = fmaf(d, (float)v[0], a.x);
    a.y = fmaf(d, (float)v[1], a.y);
    a.z = fmaf(d, (float)v[2], a.z);
    a.w = fmaf(d, (float)v[3], a.w);
}

// ---- merged prep: edge fill (0..390) + bounds (391) + wsplit (392..583)
//      + x->fp16 cast (584..3708; NO deg scaling so no cnt dependency)
__global__ void k_prep(const int* __restrict__ src, const int* __restrict__ dst,
                       int* cnt, ushort_t* csr16,
                       const int* __restrict__ batch, int* bound, int* counts,
                       const float* __restrict__ W0, const float* __restrict__ W1,
                       const float* __restrict__ W2, ushort_t* Whi, ushort_t* Wlo,
                       const float* __restrict__ x, _Float16* __restrict__ X16) {
    int b = blockIdx.x, t = threadIdx.x;
    if (b < 391) {
        int base = (b * 256 + t) * 8;
        if (base + 7 < N_EDGES) {
            int4 da = *(const int4*)(dst + base);
            int4 db = *(const int4*)(dst + base + 4);
            int4 sa = *(const int4*)(src + base);
            int4 sb = *(const int4*)(src + base + 4);
            int p0 = atomicAdd(&cnt[da.x], 1);
            int p1 = atomicAdd(&cnt[da.y], 1);
            int p2 = atomicAdd(&cnt[da.z], 1);
            int p3 = atomicAdd(&cnt[da.w], 1);
            int p4 = atomicAdd(&cnt[db.x], 1);
            int p5 = atomicAdd(&cnt[db.y], 1);
            int p6 = atomicAdd(&cnt[db.z], 1);
            int p7 = atomicAdd(&cnt[db.w], 1);
            if (p0 < CAP) csr16[da.x * CAP + p0] = (ushort_t)sa.x;
            if (p1 < CAP) csr16[da.y * CAP + p1] = (ushort_t)sa.y;
            if (p2 < CAP) csr16[da.z * CAP + p2] = (ushort_t)sa.z;
            if (p3 < CAP) csr16[da.w * CAP + p3] = (ushort_t)sa.w;
            if (p4 < CAP) csr16[db.x * CAP + p4] = (ushort_t)sb.x;
            if (p5 < CAP) csr16[db.y * CAP + p5] = (ushort_t)sb.y;
            if (p6 < CAP) csr16[db.z * CAP + p6] = (ushort_t)sb.z;
            if (p7 < CAP) csr16[db.w * CAP + p7] = (ushort_t)sb.w;
        } else {
            for (int i = base; i < N_EDGES; i++) {
                int d = dst[i];
                int slot = atomicAdd(&cnt[d], 1);
                if (slot < CAP) csr16[d * CAP + slot] = (ushort_t)src[i];
            }
        }
    } else if (b == 391) {
        int g = t;
        if (g <= NGRAPH) {
            int lo = 0, hi = N_NODES;
            while (lo < hi) {
                int mid = (lo + hi) >> 1;
                if (batch[mid] < g) lo = mid + 1; else hi = mid;
            }
            bound[g] = lo;
        }
        __syncthreads();
        if (g < NGRAPH) counts[g] = bound[g + 1] - bound[g];
    } else if (b < 584) {
        int gid = (b - 392) * 256 + t;          // 192*256 = 49152 items
        int l = gid / (32 * 512);
        int rem = gid - l * 32 * 512;
        int tile = rem >> 9;
        int p = rem & 511;
        int lane = p >> 3, j = p & 7;
        int kk = tile >> 3, c = tile & 7;
        int k = 32 * kk + (lane >> 4) * 8 + j;
        int n = 16 * c + (lane & 15);
        const float* W = (l == 0) ? W0 : (l == 1) ? W1 : W2;
        float xv = W[k * 128 + n];
        ushort_t hi = f2bf(xv);
        ushort_t lo = f2bf(xv - bf2f(hi));
        Whi[l * 16384 + rem] = hi;
        Wlo[l * 16384 + rem] = lo;
    } else {
        int gid = (b - 584) * 256 + t;          // 3125*256 = 800000 exact
        int i = gid >> 4, seg = gid & 15;       // seg: 8-feature octet
        const f32x4* px = (const f32x4*)(x + (size_t)i * HID + seg * 8);
        f32x4 a = px[0], bb = px[1];
        f16x8 o;
        o[0] = (_Float16)a.x;  o[1] = (_Float16)a.y;
        o[2] = (_Float16)a.z;  o[3] = (_Float16)a.w;
        o[4] = (_Float16)bb.x; o[5] = (_Float16)bb.y;
        o[6] = (_Float16)bb.z; o[7] = (_Float16)bb.w;
        *(f16x8*)(X16 + (size_t)i * HID + seg * 8) = o;
    }
}

// ---------------- fused layer (round-7-verified control flow) ---------------------
// pre_scaled=1: table rows already contain isd_j * h_j (r7 tiers, verbatim).
// pre_scaled=0: table rows are raw fp16(x); weight each neighbor by rsqrt(cnt[s]+1)
//               (round-0-verified 8-edge structure with per-neighbor d loads).
// pool=1: block pool-reduce + fused head: last 64 blocks to finish each run one
//         graph of the head after spinning on the done counter.
__global__ void k_layer(const _Float16* __restrict__ In,
                        const ushort_t* __restrict__ csr16, const int* __restrict__ cnt,
                        const ushort_t* __restrict__ Whi, const ushort_t* __restrict__ Wlo,
                        const float* __restrict__ bias, int pre_scaled, int scale_out,
                        int pool, const int* __restrict__ batch,
                        float* sums, float* maxs, _Float16* __restrict__ Out,
                        int* done, const int* __restrict__ counts,
                        const float* __restrict__ Wa, const float* __restrict__ ba,
                        float* __restrict__ out) {
    __shared__ float T[16][132];
    __shared__ int sg[16];
    __shared__ int sord;
    int t = threadIdx.x, wv = t >> 6, lane = t & 63;
    int hl = lane & 31, q = lane >> 5;   // half-lane, half-index
    if (pool && t < 16) sg[t] = batch[blockIdx.x * 16 + t];

    // ---- gather phase: wave wv aggregates nodes (block*16 + wv*4 + r)
    for (int r = 0; r < 4; r++) {
        int i = blockIdx.x * 16 + wv * 4 + r;      // 3125*16 = 50000 exact
        int ci = cnt[i];
        int m = min(ci, CAP);
        float isdi = rsqrtf((float)ci + 1.0f);
        int packed = ((const int*)(csr16 + (size_t)i * CAP))[hl];
        float4 a0 = make_float4(0.f, 0.f, 0.f, 0.f);
        float4 a1 = a0, a2 = a0, a3 = a0;
        if (q == 0) {
            f16x4 sv = *(const f16x4*)(In + (size_t)i * HID + hl * 4);
            float sfac = pre_scaled ? 1.0f : isdi;
            fmad4h(a0, sfac, sv);                  // self term
        }
        int e = 0;
        if (pre_scaled) {
            for (; e + 15 < m; e += 16) {          // 8 gathers in flight per lane
                int k0 = e >> 1;
                int p0 = __shfl(packed, k0);
                int p1 = __shfl(packed, k0 + 1);
                int p2 = __shfl(packed, k0 + 2);
                int p3 = __shfl(packed, k0 + 3);
                int p4 = __shfl(packed, k0 + 4);
                int p5 = __shfl(packed, k0 + 5);
                int p6 = __shfl(packed, k0 + 6);
                int p7 = __shfl(packed, k0 + 7);
                int s0 = q ? exhi(p0) : exlo(p0);
                int s1 = q ? exhi(p1) : exlo(p1);
                int s2 = q ? exhi(p2) : exlo(p2);
                int s3 = q ? exhi(p3) : exlo(p3);
                int s4 = q ? exhi(p4) : exlo(p4);
                int s5 = q ? exhi(p5) : exlo(p5);
                int s6 = q ? exhi(p6) : exlo(p6);
                int s7 = q ? exhi(p7) : exlo(p7);
                f16x4 v0 = *(const f16x4*)(In + (size_t)s0 * HID + hl * 4);
                f16x4 v1 = *(const f16x4*)(In + (size_t)s1 * HID + hl * 4);
                f16x4 v2 = *(const f16x4*)(In + (size_t)s2 * HID + hl * 4);
                f16x4 v3 = *(const f16x4*)(In + (size_t)s3 * HID + hl * 4);
                f16x4 v4 = *(const f16x4*)(In + (size_t)s4 * HID + hl * 4);
                f16x4 v5 = *(const f16x4*)(In + (size_t)s5 * HID + hl * 4);
                f16x4 v6 = *(const f16x4*)(In + (size_t)s6 * HID + hl * 4);
                f16x4 v7 = *(const f16x4*)(In + (size_t)s7 * HID + hl * 4);
                add4h(a0, v0); add4h(a1, v1); add4h(a2, v2); add4h(a3, v3);
                add4h(a0, v4); add4h(a1, v5); add4h(a2, v6); add4h(a3, v7);
            }
            for (; e + 7 < m; e += 8) {
                int k0 = e >> 1;
                int p0 = __shfl(packed, k0);
                int p1 = __shfl(packed, k0 + 1);
                int p2 = __shfl(packed, k0 + 2);
                int p3 = __shfl(packed, k0 + 3);
                int s0 = q ? exhi(p0) : exlo(p0);
                int s1 = q ? exhi(p1) : exlo(p1);
                int s2 = q ? exhi(p2) : exlo(p2);
                int s3 = q ? exhi(p3) : exlo(p3);
                f16x4 v0 = *(const f16x4*)(In + (size_t)s0 * HID + hl * 4);
                f16x4 v1 = *(const f16x4*)(In + (size_t)s1 * HID + hl * 4);
                f16x4 v2 = *(const f16x4*)(In + (size_t)s2 * HID + hl * 4);
                f16x4 v3 = *(const f16x4*)(In + (size_t)s3 * HID + hl * 4);
                add4h(a0, v0); add4h(a1, v1); add4h(a2, v2); add4h(a3, v3);
            }
            for (; e + 1 < m; e += 2) {
                int p = __shfl(packed, e >> 1);
                int s0 = q ? exhi(p) : exlo(p);
                f16x4 v0 = *(const f16x4*)(In + (size_t)s0 * HID + hl * 4);
                add4h(a0, v0);
            }
            if (e < m && q == 0) {
                int p = __shfl(packed, e >> 1);
                int s0 = exlo(p);
                f16x4 v0 = *(const f16x4*)(In + (size_t)s0 * HID + hl * 4);
                add4h(a0, v0);
            }
        } else {
            for (; e + 7 < m; e += 8) {            // round-0 structure, fp16 loads
                int k0 = e >> 1;
                int p0 = __shfl(packed, k0);
                int p1 = __shfl(packed, k0 + 1);
                int p2 = __shfl(packed, k0 + 2);
                int p3 = __shfl(packed, k0 + 3);
                int s0 = q ? exhi(p0) : exlo(p0);
                int s1 = q ? exhi(p1) : exlo(p1);
                int s2 = q ? exhi(p2) : exlo(p2);
                int s3 = q ? exhi(p3) : exlo(p3);
                float d0 = rsqrtf((float)cnt[s0] + 1.0f);
                float d1 = rsqrtf((float)cnt[s1] + 1.0f);
                float d2 = rsqrtf((float)cnt[s2] + 1.0f);
                float d3 = rsqrtf((float)cnt[s3] + 1.0f);
                f16x4 v0 = *(const f16x4*)(In + (size_t)s0 * HID + hl * 4);
                f16x4 v1 = *(const f16x4*)(In + (size_t)s1 * HID + hl * 4);
                f16x4 v2 = *(const f16x4*)(In + (size_t)s2 * HID + hl * 4);
                f16x4 v3 = *(const f16x4*)(In + (size_t)s3 * HID + hl * 4);
                fmad4h(a0, d0, v0); fmad4h(a1, d1, v1);
                fmad4h(a2, d2, v2); fmad4h(a3, d3, v3);
            }
            for (; e + 1 < m; e += 2) {
                int p = __shfl(packed, e >> 1);
                int s0 = q ? exhi(p) : exlo(p);
                float d0 = rsqrtf((float)cnt[s0] + 1.0f);
                f16x4 v0 = *(const f16x4*)(In + (size_t)s0 * HID + hl * 4);
                fmad4h(a0, d0, v0);
            }
            if (e < m && q == 0) {
                int p = __shfl(packed, e >> 1);
                int s0 = exlo(p);
                float d0 = rsqrtf((float)cnt[s0] + 1.0f);
                f16x4 v0 = *(const f16x4*)(In + (size_t)s0 * HID + hl * 4);
                fmad4h(a0, d0, v0);
            }
        }
        float4 s4;
        s4.x = (a0.x + a1.x) + (a2.x + a3.x);
        s4.y = (a0.y + a1.y) + (a2.y + a3.y);
        s4.z = (a0.z + a1.z) + (a2.z + a3.z);
        s4.w = (a0.w + a1.w) + (a2.w + a3.w);
        s4.x += __shfl_xor(s4.x, 32);
        s4.y += __shfl_xor(s4.y, 32);
        s4.z += __shfl_xor(s4.z, 32);
        s4.w += __shfl_xor(s4.w, 32);
        if (q == 0) {
            float4 o;
            o.x = isdi * s4.x; o.y = isdi * s4.y;
            o.z = isdi * s4.z; o.w = isdi * s4.w;
            *(float4*)&T[wv * 4 + r][hl * 4] = o;
        }
    }
    __syncthreads();

    // ---- MFMA phase: wave wv -> cols [wv*32, wv*32+32)
    int mrow = lane & 15, qq = lane >> 4;
    f32x4 acc[2];
    acc[0] = (f32x4){0.f, 0.f, 0.f, 0.f};
    acc[1] = (f32x4){0.f, 0.f, 0.f, 0.f};
#pragma unroll
    for (int kk = 0; kk < 4; kk++) {
        const float* tp = &T[mrow][kk * 32 + qq * 8];
        float4 p0 = *(const float4*)tp;
        float4 p1 = *(const float4*)(tp + 4);
        float av[8] = {p0.x, p0.y, p0.z, p0.w, p1.x, p1.y, p1.z, p1.w};
        bf16x8 ahi, alo;
#pragma unroll
        for (int j = 0; j < 8; j++) {
            ushort_t hbits = f2bf(av[j]);
            ahi[j] = (short)hbits;
            alo[j] = (short)f2bf(av[j] - bf2f(hbits));
        }
#pragma unroll
        for (int cl = 0; cl < 2; cl++) {
            int c = wv * 2 + cl;
            const bf16x8 bhi = *(const bf16x8*)(Whi + (((kk * 8 + c) * 64 + lane) << 3));
            const bf16x8 blo = *(const bf16x8*)(Wlo + (((kk * 8 + c) * 64 + lane) << 3));
            acc[cl] = __builtin_amdgcn_mfma_f32_16x16x32_bf16(ahi, bhi, acc[cl], 0, 0, 0);
            acc[cl] = __builtin_amdgcn_mfma_f32_16x16x32_bf16(alo, bhi, acc[cl], 0, 0, 0);
            acc[cl] = __builtin_amdgcn_mfma_f32_16x16x32_bf16(ahi, blo, acc[cl], 0, 0, 0);
        }
    }
    // epilogue: C/D col = mrow, row = qq*4+rr
    int rb = blockIdx.x * 16 + qq * 4;
    if (!pool) {
        float osc[4];
#pragma unroll
        for (int rr = 0; rr < 4; rr++)
            osc[rr] = scale_out ? rsqrtf((float)cnt[rb + rr] + 1.0f) : 1.0f;
#pragma unroll
        for (int cl = 0; cl < 2; cl++) {
            int col = (wv * 2 + cl) * 16 + mrow;
            float bcol = bias[col];
#pragma unroll
            for (int rr = 0; rr < 4; rr++) {
                float val = fmaxf(acc[cl][rr] + bcol, 0.f);
                Out[(size_t)(rb + rr) * HID + col] = (_Float16)(val * osc[rr]);
            }
        }
    } else {
        // write relu'd values back into T (rows x feats), then block pool-reduce
        __syncthreads();   // all waves done reading T
#pragma unroll
        for (int cl = 0; cl < 2; cl++) {
            int col = (wv * 2 + cl) * 16 + mrow;
            float bcol = bias[col];
#pragma unroll
            for (int rr = 0; rr < 4; rr++)
                T[qq * 4 + rr][col] = fmaxf(acc[cl][rr] + bcol, 0.f);
        }
        __syncthreads();
        int f = t & 127, half = t >> 7;   // half 0: sums, half 1: maxs
        int cur = sg[0];
        float s = 0.f, mx = 0.f;
        for (int r = 0; r < 16; r++) {
            int g = sg[r];
            if (g != cur) {
                if (half == 0) atomicAdd(&sums[cur * HID + f], s);
                else atomicMax((int*)&maxs[cur * HID + f], __float_as_int(mx));
                s = 0.f; mx = 0.f; cur = g;
            }
            float v = T[r][f];
            s += v;
            mx = fmaxf(mx, v);
        }
        if (half == 0) atomicAdd(&sums[cur * HID + f], s);
        else atomicMax((int*)&maxs[cur * HID + f], __float_as_int(mx));

        // ---- fused head: last NGRAPH blocks to finish each handle one graph
        __threadfence();               // make this thread's atomics visible
        __syncthreads();               // all threads' atomics issued + fenced
        if (t == 0) sord = atomicAdd(done, 1);
        __syncthreads();
        int ord = sord;
        if (ord >= NTILES - NGRAPH) {
            int g = ord - (NTILES - NGRAPH);
            if (t == 0) { while (atomicAdd(done, 0) < NTILES) {} }
            __syncthreads();           // all 3125 blocks' pool atomics complete
            float* a = &T[0][0];       // reuse LDS (2112 floats available)
            float denom = fmaxf((float)counts[g], 1.f);
            float val;
            if (t < 128) val = atomicAdd(&sums[g * HID + t], 0.0f) / denom;
            else val = __int_as_float(atomicMax((int*)&maxs[g * HID + (t - 128)], 0));
            a[t] = val;
            out[NGRAPH * NCLS + g * 256 + t] = val;
            __syncthreads();
            for (int c = 0; c < NCLS; c++) {
                float p = a[t] * Wa[t * NCLS + c];
                for (int o = 32; o > 0; o >>= 1) p += __shfl_down(p, o);
                if ((t & 63) == 0) a[256 + (t >> 6)] = p;
                __syncthreads();
                if (t == 0)
                    out[g * NCLS + c] = a[256] + a[257] + a[258] + a[259] + ba[c];
                __syncthreads();
            }
        }
    }
}

extern "C" void kernel_launch(void* const* d_in, const int* in_sizes, int n_in,
                              void* d_out, int out_size, void* d_ws, size_t ws_size,
                              hipStream_t stream) {
    const float* x = (const float*)d_in[0];
    const int* ei = (const int*)d_in[1];
    const int* src = ei;
    const int* dst = ei + N_EDGES;
    const int* batch = (const int*)d_in[2];
    const float* W0 = (const float*)d_in[3];
    const float* b0 = (const float*)d_in[4];
    const float* W1 = (const float*)d_in[5];
    const float* b1 = (const float*)d_in[6];
    const float* W2 = (const float*)d_in[7];
    const float* b2 = (const float*)d_in[8];
    const float* Wa = (const float*)d_in[9];
    const float* ba = (const float*)d_in[10];
    float* out = (float*)d_out;

    char* ws = (char*)d_ws;
    int*       cnt    = (int*)(ws + 0);             // 50000 i32
    int*       bound  = (int*)(ws + 200192);        // 65 i32 (ends 200452)
    int*       done   = (int*)(ws + 200512);        // 1 i32 completion counter
    int*       counts = (int*)(ws + 200576);        // 64 i32
    float*     sums   = (float*)(ws + 200832);      // 8192 f32
    float*     maxs   = (float*)(ws + 233600);      // 8192 f32
    ushort_t*  Whi    = (ushort_t*)(ws + 266368);   // 3*16384 bf16
    ushort_t*  Wlo    = (ushort_t*)(ws + 364672);   // 3*16384 bf16
    ushort_t*  csr16  = (ushort_t*)(ws + 462976);   // 50000*64 u16 (6.4 MB)
    _Float16*  X16    = (_Float16*)(ws + 7462976);  // 50000x128 f16 (12.8 MB)
    _Float16*  hA     = (_Float16*)(ws + 20262976); // 50000x128 f16
    _Float16*  hB     = (_Float16*)(ws + 33062976); // 50000x128 f16
    // total 45,862,976 B

    // zero cnt/bound/done/counts/sums/maxs in one capture-safe memset
    hipMemsetAsync(ws, 0, 266368, stream);
    // prep: edge fill + bounds + wsplit + fp16 cast of x (no deg dependency)
    k_prep<<<3709, 256, 0, stream>>>(src, dst, cnt, csr16, batch, bound, counts,
                                     W0, W1, W2, Whi, Wlo, x, X16);

    // layer 1: non-prescaled gather (per-neighbor rsqrt), prescaled fp16 output
    k_layer<<<NTILES, 256, 0, stream>>>(X16, csr16, cnt, Whi, Wlo, b0, 0, 1,
                                        0, batch, sums, maxs, hA,
                                        done, counts, Wa, ba, out);
    // layer 2: prescaled gather, prescaled output
    k_layer<<<NTILES, 256, 0, stream>>>(hA, csr16, cnt, Whi + 16384, Wlo + 16384, b1, 1, 1,
                                        0, batch, sums, maxs, hB,
                                        done, counts, Wa, ba, out);
    // layer 3: prescaled gather, pool + fused head (last 64 blocks run the head)
    k_layer<<<NTILES, 256, 0, stream>>>(hB, csr16, cnt, Whi + 32768, Wlo + 32768, b2, 1, 0,
                                        1, batch, sums, maxs, hA,
                                        done, counts, Wa, ba, out);
}

// Round 11
// 275.576 us; speedup vs baseline: 5.4433x; 1.8659x over previous
//
#include <hip/hip_runtime.h>
#include <stdint.h>

#define N_NODES 50000
#define N_EDGES 800000
#define HID 128
#define NCLS 10
#define NGRAPH 64
#define CAP 64   // bucket capacity; deg ~ Poisson(16), P(max>64) < 1e-20
#define NTILES 3125

typedef unsigned short ushort_t;
typedef __attribute__((ext_vector_type(8))) short bf16x8;
typedef __attribute__((ext_vector_type(4))) float f32x4;
typedef __attribute__((ext_vector_type(4))) _Float16 f16x4;
typedef __attribute__((ext_vector_type(8))) _Float16 f16x8;

__device__ __forceinline__ ushort_t f2bf(float f) {
    union { float f; unsigned int i; } v; v.f = f;
    unsigned int u = v.i;
    return (ushort_t)((u + 0x7FFFu + ((u >> 16) & 1u)) >> 16);
}
__device__ __forceinline__ float bf2f(ushort_t u) {
    union { unsigned int i; float f; } v; v.i = ((unsigned int)u) << 16; return v.f;
}
// UNSIGNED extraction — (p>>16) on signed int sign-extends for ids>=32768
__device__ __forceinline__ int exhi(int p) { return (p >> 16) & 0xffff; }
__device__ __forceinline__ int exlo(int p) { return p & 0xffff; }
__device__ __forceinline__ void add4h(float4& a, f16x4 v) {
    a.x += (float)v[0];
    a.y += (float)v[1];
    a.z += (float)v[2];
    a.w += (float)v[3];
}
__device__ __forceinline__ void fmad4h(float4& a, float d, f16x4 v) {
    a.x = fmaf(d, (float)v[0], a.x);
    a.y = fmaf(d, (float)v[1], a.y);
    a.z = fmaf(d, (float)v[2], a.z);
    a.w = fmaf(d, (float)v[3], a.w);
}

// ---- merged prep:
//   blocks 0..3124      : edge fill, 1 edge/thread (800000 exact) — latency-bound,
//                         so give it ~12 blocks/CU instead of r10's 1.5 (the ~100us fix)
//   block  3125         : graph bounds + counts
//   blocks 3126..3317   : weight hi/lo split (49152 items)
//   blocks 3318..6442   : x -> fp16 cast, UNSCALED (no cnt dependency; L1 scales)
__global__ void k_prep(const int* __restrict__ src, const int* __restrict__ dst,
                       int* cnt, ushort_t* csr16,
                       const int* __restrict__ batch, int* bound, int* counts,
                       const float* __restrict__ W0, const float* __restrict__ W1,
                       const float* __restrict__ W2, ushort_t* Whi, ushort_t* Wlo,
                       const float* __restrict__ x, _Float16* __restrict__ X16) {
    int b = blockIdx.x, t = threadIdx.x;
    if (b < 3125) {
        int e = b * 256 + t;                    // 3125*256 = 800000 exact
        int d = dst[e];
        int s = src[e];
        int slot = atomicAdd(&cnt[d], 1);
        if (slot < CAP) csr16[d * CAP + slot] = (ushort_t)s;
    } else if (b == 3125) {
        int g = t;
        if (g <= NGRAPH) {
            int lo = 0, hi = N_NODES;
            while (lo < hi) {
                int mid = (lo + hi) >> 1;
                if (batch[mid] < g) lo = mid + 1; else hi = mid;
            }
            bound[g] = lo;
        }
        __syncthreads();
        if (g < NGRAPH) counts[g] = bound[g + 1] - bound[g];
    } else if (b < 3318) {
        int gid = (b - 3126) * 256 + t;         // 192*256 = 49152 items
        int l = gid / (32 * 512);
        int rem = gid - l * 32 * 512;
        int tile = rem >> 9;
        int p = rem & 511;
        int lane = p >> 3, j = p & 7;
        int kk = tile >> 3, c = tile & 7;
        int k = 32 * kk + (lane >> 4) * 8 + j;
        int n = 16 * c + (lane & 15);
        const float* W = (l == 0) ? W0 : (l == 1) ? W1 : W2;
        float xv = W[k * 128 + n];
        ushort_t hi = f2bf(xv);
        ushort_t lo = f2bf(xv - bf2f(hi));
        Whi[l * 16384 + rem] = hi;
        Wlo[l * 16384 + rem] = lo;
    } else {
        int gid = (b - 3318) * 256 + t;         // 3125*256 = 800000 exact
        int i = gid >> 4, seg = gid & 15;       // seg: 8-feature octet
        const f32x4* px = (const f32x4*)(x + (size_t)i * HID + seg * 8);
        f32x4 a = px[0], bb = px[1];
        f16x8 o;
        o[0] = (_Float16)a.x;  o[1] = (_Float16)a.y;
        o[2] = (_Float16)a.z;  o[3] = (_Float16)a.w;
        o[4] = (_Float16)bb.x; o[5] = (_Float16)bb.y;
        o[6] = (_Float16)bb.z; o[7] = (_Float16)bb.w;
        *(f16x8*)(X16 + (size_t)i * HID + seg * 8) = o;
    }
}

// ---------------- fused layer (round-7/round-10-verified control flow) ------------
// pre_scaled=1: table rows already contain isd_j * h_j (r7 tiers, verbatim).
// pre_scaled=0: table rows are raw fp16(x); weight each neighbor by rsqrt(cnt[s]+1)
//               (round-0/round-10-verified 8-edge structure).
__global__ void k_layer(const _Float16* __restrict__ In,
                        const ushort_t* __restrict__ csr16, const int* __restrict__ cnt,
                        const ushort_t* __restrict__ Whi, const ushort_t* __restrict__ Wlo,
                        const float* __restrict__ bias, int pre_scaled, int scale_out,
                        int pool, const int* __restrict__ batch,
                        float* sums, float* maxs, _Float16* __restrict__ Out) {
    __shared__ float T[16][132];
    __shared__ int sg[16];
    int t = threadIdx.x, wv = t >> 6, lane = t & 63;
    int hl = lane & 31, q = lane >> 5;   // half-lane, half-index
    if (pool && t < 16) sg[t] = batch[blockIdx.x * 16 + t];

    // ---- gather phase: wave wv aggregates nodes (block*16 + wv*4 + r)
    for (int r = 0; r < 4; r++) {
        int i = blockIdx.x * 16 + wv * 4 + r;      // 3125*16 = 50000 exact
        int ci = cnt[i];
        int m = min(ci, CAP);
        float isdi = rsqrtf((float)ci + 1.0f);
        int packed = ((const int*)(csr16 + (size_t)i * CAP))[hl];
        float4 a0 = make_float4(0.f, 0.f, 0.f, 0.f);
        float4 a1 = a0, a2 = a0, a3 = a0;
        if (q == 0) {
            f16x4 sv = *(const f16x4*)(In + (size_t)i * HID + hl * 4);
            float sfac = pre_scaled ? 1.0f : isdi;
            fmad4h(a0, sfac, sv);                  // self term
        }
        int e = 0;
        if (pre_scaled) {
            for (; e + 15 < m; e += 16) {          // 8 gathers in flight per lane
                int k0 = e >> 1;
                int p0 = __shfl(packed, k0);
                int p1 = __shfl(packed, k0 + 1);
                int p2 = __shfl(packed, k0 + 2);
                int p3 = __shfl(packed, k0 + 3);
                int p4 = __shfl(packed, k0 + 4);
                int p5 = __shfl(packed, k0 + 5);
                int p6 = __shfl(packed, k0 + 6);
                int p7 = __shfl(packed, k0 + 7);
                int s0 = q ? exhi(p0) : exlo(p0);
                int s1 = q ? exhi(p1) : exlo(p1);
                int s2 = q ? exhi(p2) : exlo(p2);
                int s3 = q ? exhi(p3) : exlo(p3);
                int s4 = q ? exhi(p4) : exlo(p4);
                int s5 = q ? exhi(p5) : exlo(p5);
                int s6 = q ? exhi(p6) : exlo(p6);
                int s7 = q ? exhi(p7) : exlo(p7);
                f16x4 v0 = *(const f16x4*)(In + (size_t)s0 * HID + hl * 4);
                f16x4 v1 = *(const f16x4*)(In + (size_t)s1 * HID + hl * 4);
                f16x4 v2 = *(const f16x4*)(In + (size_t)s2 * HID + hl * 4);
                f16x4 v3 = *(const f16x4*)(In + (size_t)s3 * HID + hl * 4);
                f16x4 v4 = *(const f16x4*)(In + (size_t)s4 * HID + hl * 4);
                f16x4 v5 = *(const f16x4*)(In + (size_t)s5 * HID + hl * 4);
                f16x4 v6 = *(const f16x4*)(In + (size_t)s6 * HID + hl * 4);
                f16x4 v7 = *(const f16x4*)(In + (size_t)s7 * HID + hl * 4);
                add4h(a0, v0); add4h(a1, v1); add4h(a2, v2); add4h(a3, v3);
                add4h(a0, v4); add4h(a1, v5); add4h(a2, v6); add4h(a3, v7);
            }
            for (; e + 7 < m; e += 8) {
                int k0 = e >> 1;
                int p0 = __shfl(packed, k0);
                int p1 = __shfl(packed, k0 + 1);
                int p2 = __shfl(packed, k0 + 2);
                int p3 = __shfl(packed, k0 + 3);
                int s0 = q ? exhi(p0) : exlo(p0);
                int s1 = q ? exhi(p1) : exlo(p1);
                int s2 = q ? exhi(p2) : exlo(p2);
                int s3 = q ? exhi(p3) : exlo(p3);
                f16x4 v0 = *(const f16x4*)(In + (size_t)s0 * HID + hl * 4);
                f16x4 v1 = *(const f16x4*)(In + (size_t)s1 * HID + hl * 4);
                f16x4 v2 = *(const f16x4*)(In + (size_t)s2 * HID + hl * 4);
                f16x4 v3 = *(const f16x4*)(In + (size_t)s3 * HID + hl * 4);
                add4h(a0, v0); add4h(a1, v1); add4h(a2, v2); add4h(a3, v3);
            }
            for (; e + 1 < m; e += 2) {
                int p = __shfl(packed, e >> 1);
                int s0 = q ? exhi(p) : exlo(p);
                f16x4 v0 = *(const f16x4*)(In + (size_t)s0 * HID + hl * 4);
                add4h(a0, v0);
            }
            if (e < m && q == 0) {
                int p = __shfl(packed, e >> 1);
                int s0 = exlo(p);
                f16x4 v0 = *(const f16x4*)(In + (size_t)s0 * HID + hl * 4);
                add4h(a0, v0);
            }
        } else {
            for (; e + 7 < m; e += 8) {            // round-0 structure, fp16 loads
                int k0 = e >> 1;
                int p0 = __shfl(packed, k0);
                int p1 = __shfl(packed, k0 + 1);
                int p2 = __shfl(packed, k0 + 2);
                int p3 = __shfl(packed, k0 + 3);
                int s0 = q ? exhi(p0) : exlo(p0);
                int s1 = q ? exhi(p1) : exlo(p1);
                int s2 = q ? exhi(p2) : exlo(p2);
                int s3 = q ? exhi(p3) : exlo(p3);
                float d0 = rsqrtf((float)cnt[s0] + 1.0f);
                float d1 = rsqrtf((float)cnt[s1] + 1.0f);
                float d2 = rsqrtf((float)cnt[s2] + 1.0f);
                float d3 = rsqrtf((float)cnt[s3] + 1.0f);
                f16x4 v0 = *(const f16x4*)(In + (size_t)s0 * HID + hl * 4);
                f16x4 v1 = *(const f16x4*)(In + (size_t)s1 * HID + hl * 4);
                f16x4 v2 = *(const f16x4*)(In + (size_t)s2 * HID + hl * 4);
                f16x4 v3 = *(const f16x4*)(In + (size_t)s3 * HID + hl * 4);
                fmad4h(a0, d0, v0); fmad4h(a1, d1, v1);
                fmad4h(a2, d2, v2); fmad4h(a3, d3, v3);
            }
            for (; e + 1 < m; e += 2) {
                int p = __shfl(packed, e >> 1);
                int s0 = q ? exhi(p) : exlo(p);
                float d0 = rsqrtf((float)cnt[s0] + 1.0f);
                f16x4 v0 = *(const f16x4*)(In + (size_t)s0 * HID + hl * 4);
                fmad4h(a0, d0, v0);
            }
            if (e < m && q == 0) {
                int p = __shfl(packed, e >> 1);
                int s0 = exlo(p);
                float d0 = rsqrtf((float)cnt[s0] + 1.0f);
                f16x4 v0 = *(const f16x4*)(In + (size_t)s0 * HID + hl * 4);
                fmad4h(a0, d0, v0);
            }
        }
        float4 s4;
        s4.x = (a0.x + a1.x) + (a2.x + a3.x);
        s4.y = (a0.y + a1.y) + (a2.y + a3.y);
        s4.z = (a0.z + a1.z) + (a2.z + a3.z);
        s4.w = (a0.w + a1.w) + (a2.w + a3.w);
        s4.x += __shfl_xor(s4.x, 32);
        s4.y += __shfl_xor(s4.y, 32);
        s4.z += __shfl_xor(s4.z, 32);
        s4.w += __shfl_xor(s4.w, 32);
        if (q == 0) {
            float4 o;
            o.x = isdi * s4.x; o.y = isdi * s4.y;
            o.z = isdi * s4.z; o.w = isdi * s4.w;
            *(float4*)&T[wv * 4 + r][hl * 4] = o;
        }
    }
    __syncthreads();

    // ---- MFMA phase: wave wv -> cols [wv*32, wv*32+32)
    int mrow = lane & 15, qq = lane >> 4;
    f32x4 acc[2];
    acc[0] = (f32x4){0.f, 0.f, 0.f, 0.f};
    acc[1] = (f32x4){0.f, 0.f, 0.f, 0.f};
#pragma unroll
    for (int kk = 0; kk < 4; kk++) {
        const float* tp = &T[mrow][kk * 32 + qq * 8];
        float4 p0 = *(const float4*)tp;
        float4 p1 = *(const float4*)(tp + 4);
        float av[8] = {p0.x, p0.y, p0.z, p0.w, p1.x, p1.y, p1.z, p1.w};
        bf16x8 ahi, alo;
#pragma unroll
        for (int j = 0; j < 8; j++) {
            ushort_t hbits = f2bf(av[j]);
            ahi[j] = (short)hbits;
            alo[j] = (short)f2bf(av[j] - bf2f(hbits));
        }
#pragma unroll
        for (int cl = 0; cl < 2; cl++) {
            int c = wv * 2 + cl;
            const bf16x8 bhi = *(const bf16x8*)(Whi + (((kk * 8 + c) * 64 + lane) << 3));
            const bf16x8 blo = *(const bf16x8*)(Wlo + (((kk * 8 + c) * 64 + lane) << 3));
            acc[cl] = __builtin_amdgcn_mfma_f32_16x16x32_bf16(ahi, bhi, acc[cl], 0, 0, 0);
            acc[cl] = __builtin_amdgcn_mfma_f32_16x16x32_bf16(alo, bhi, acc[cl], 0, 0, 0);
            acc[cl] = __builtin_amdgcn_mfma_f32_16x16x32_bf16(ahi, blo, acc[cl], 0, 0, 0);
        }
    }
    // epilogue: C/D col = mrow, row = qq*4+rr
    int rb = blockIdx.x * 16 + qq * 4;
    if (!pool) {
        float osc[4];
#pragma unroll
        for (int rr = 0; rr < 4; rr++)
            osc[rr] = scale_out ? rsqrtf((float)cnt[rb + rr] + 1.0f) : 1.0f;
#pragma unroll
        for (int cl = 0; cl < 2; cl++) {
            int col = (wv * 2 + cl) * 16 + mrow;
            float bcol = bias[col];
#pragma unroll
            for (int rr = 0; rr < 4; rr++) {
                float val = fmaxf(acc[cl][rr] + bcol, 0.f);
                Out[(size_t)(rb + rr) * HID + col] = (_Float16)(val * osc[rr]);
            }
        }
    } else {
        // write relu'd values back into T (rows x feats), then block pool-reduce
        __syncthreads();   // all waves done reading T
#pragma unroll
        for (int cl = 0; cl < 2; cl++) {
            int col = (wv * 2 + cl) * 16 + mrow;
            float bcol = bias[col];
#pragma unroll
            for (int rr = 0; rr < 4; rr++)
                T[qq * 4 + rr][col] = fmaxf(acc[cl][rr] + bcol, 0.f);
        }
        __syncthreads();
        int f = t & 127, half = t >> 7;   // half 0: sums, half 1: maxs
        int cur = sg[0];
        float s = 0.f, mx = 0.f;
        for (int r = 0; r < 16; r++) {
            int g = sg[r];
            if (g != cur) {
                if (half == 0) atomicAdd(&sums[cur * HID + f], s);
                else atomicMax((int*)&maxs[cur * HID + f], __float_as_int(mx));
                s = 0.f; mx = 0.f; cur = g;
            }
            float v = T[r][f];
            s += v;
            mx = fmaxf(mx, v);
        }
        if (half == 0) atomicAdd(&sums[cur * HID + f], s);
        else atomicMax((int*)&maxs[cur * HID + f], __float_as_int(mx));
    }
}

// ---------------- head ----------------
__global__ void k_final(const float* __restrict__ sums, const float* __restrict__ maxs,
                        const int* __restrict__ counts, const float* __restrict__ Wa,
                        const float* __restrict__ ba, float* __restrict__ out) {
    __shared__ float a[256];
    __shared__ float red[4];
    int g = blockIdx.x, t = threadIdx.x;
    float denom = fmaxf((float)counts[g], 1.f);
    float val = (t < 128) ? (sums[g * HID + t] / denom) : maxs[g * HID + (t - 128)];
    a[t] = val;
    out[NGRAPH * NCLS + g * 256 + t] = val;
    __syncthreads();
    for (int c = 0; c < NCLS; c++) {
        float p = a[t] * Wa[t * NCLS + c];
        for (int o = 32; o > 0; o >>= 1) p += __shfl_down(p, o);
        if ((t & 63) == 0) red[t >> 6] = p;
        __syncthreads();
        if (t == 0) {
            out[g * NCLS + c] = red[0] + red[1] + red[2] + red[3] + ba[c];
        }
        __syncthreads();
    }
}

extern "C" void kernel_launch(void* const* d_in, const int* in_sizes, int n_in,
                              void* d_out, int out_size, void* d_ws, size_t ws_size,
                              hipStream_t stream) {
    const float* x = (const float*)d_in[0];
    const int* ei = (const int*)d_in[1];
    const int* src = ei;
    const int* dst = ei + N_EDGES;
    const int* batch = (const int*)d_in[2];
    const float* W0 = (const float*)d_in[3];
    const float* b0 = (const float*)d_in[4];
    const float* W1 = (const float*)d_in[5];
    const float* b1 = (const float*)d_in[6];
    const float* W2 = (const float*)d_in[7];
    const float* b2 = (const float*)d_in[8];
    const float* Wa = (const float*)d_in[9];
    const float* ba = (const float*)d_in[10];
    float* out = (float*)d_out;

    char* ws = (char*)d_ws;
    int*       cnt    = (int*)(ws + 0);             // 50000 i32
    int*       bound  = (int*)(ws + 200192);        // 65 i32
    int*       counts = (int*)(ws + 200576);        // 64 i32
    float*     sums   = (float*)(ws + 200832);      // 8192 f32
    float*     maxs   = (float*)(ws + 233600);      // 8192 f32
    ushort_t*  Whi    = (ushort_t*)(ws + 266368);   // 3*16384 bf16
    ushort_t*  Wlo    = (ushort_t*)(ws + 364672);   // 3*16384 bf16
    ushort_t*  csr16  = (ushort_t*)(ws + 462976);   // 50000*64 u16 (6.4 MB)
    _Float16*  X16    = (_Float16*)(ws + 7462976);  // 50000x128 f16 (12.8 MB)
    _Float16*  hA     = (_Float16*)(ws + 20262976); // 50000x128 f16
    _Float16*  hB     = (_Float16*)(ws + 33062976); // 50000x128 f16
    // total 45,862,976 B

    // zero cnt/bound/counts/sums/maxs in one capture-safe memset
    hipMemsetAsync(ws, 0, 266368, stream);
    // prep: high-occupancy edge fill + bounds + wsplit + unscaled fp16 cast of x
    k_prep<<<6443, 256, 0, stream>>>(src, dst, cnt, csr16, batch, bound, counts,
                                     W0, W1, W2, Whi, Wlo, x, X16);

    // layer 1: non-prescaled gather (per-neighbor rsqrt), prescaled fp16 output
    k_layer<<<NTILES, 256, 0, stream>>>(X16, csr16, cnt, Whi, Wlo, b0, 0, 1,
                                        0, batch, sums, maxs, hA);
    // layer 2: prescaled gather, prescaled output
    k_layer<<<NTILES, 256, 0, stream>>>(hA, csr16, cnt, Whi + 16384, Wlo + 16384, b1, 1, 1,
                                        0, batch, sums, maxs, hB);
    // layer 3: prescaled gather, pool in-kernel
    k_layer<<<NTILES, 256, 0, stream>>>(hB, csr16, cnt, Whi + 32768, Wlo + 32768, b2, 1, 0,
                                        1, batch, sums, maxs, hA);

    k_final<<<NGRAPH, 256, 0, stream>>>(sums, maxs, counts, Wa, ba, out);
}

// Round 12
// 269.088 us; speedup vs baseline: 5.5746x; 1.0241x over previous
//
#include <hip/hip_runtime.h>
#include <stdint.h>

#define N_NODES 50000
#define N_EDGES 800000
#define HID 128
#define NCLS 10
#define NGRAPH 64
#define CAP 64   // bucket capacity; deg ~ Poisson(16), P(max>64) < 1e-20

typedef unsigned short ushort_t;
typedef __attribute__((ext_vector_type(8))) short bf16x8;
typedef __attribute__((ext_vector_type(4))) float f32x4;
typedef __attribute__((ext_vector_type(4))) _Float16 f16x4;
typedef __attribute__((ext_vector_type(8))) _Float16 f16x8;

__device__ __forceinline__ ushort_t f2bf(float f) {
    union { float f; unsigned int i; } v; v.f = f;
    unsigned int u = v.i;
    return (ushort_t)((u + 0x7FFFu + ((u >> 16) & 1u)) >> 16);
}
__device__ __forceinline__ float bf2f(ushort_t u) {
    union { unsigned int i; float f; } v; v.i = ((unsigned int)u) << 16; return v.f;
}
// UNSIGNED extraction — (p>>16) on signed int sign-extends for ids>=32768
__device__ __forceinline__ int exhi(int p) { return (p >> 16) & 0xffff; }
__device__ __forceinline__ int exlo(int p) { return p & 0xffff; }
// fp16 gather accumulate: a += (float)v[k]
__device__ __forceinline__ void add4h(float4& a, f16x4 v) {
    a.x += (float)v[0];
    a.y += (float)v[1];
    a.z += (float)v[2];
    a.w += (float)v[3];
}

// ---- merged prep: edge fill (blocks 0..390) + bounds (391) + wsplit (392..583)
// cnt/sums/maxs/bound/counts are pre-zeroed by hipMemsetAsync on the stream.
__global__ void k_prep(const int* __restrict__ src, const int* __restrict__ dst,
                       int* cnt, ushort_t* csr16,
                       const int* __restrict__ batch, int* bound, int* counts,
                       const float* __restrict__ W0, const float* __restrict__ W1,
                       const float* __restrict__ W2, ushort_t* Whi, ushort_t* Wlo) {
    int b = blockIdx.x, t = threadIdx.x;
    if (b < 391) {
        int base = (b * 256 + t) * 8;
        if (base + 7 < N_EDGES) {
            int4 da = *(const int4*)(dst + base);
            int4 db = *(const int4*)(dst + base + 4);
            int4 sa = *(const int4*)(src + base);
            int4 sb = *(const int4*)(src + base + 4);
            int p0 = atomicAdd(&cnt[da.x], 1);
            int p1 = atomicAdd(&cnt[da.y], 1);
            int p2 = atomicAdd(&cnt[da.z], 1);
            int p3 = atomicAdd(&cnt[da.w], 1);
            int p4 = atomicAdd(&cnt[db.x], 1);
            int p5 = atomicAdd(&cnt[db.y], 1);
            int p6 = atomicAdd(&cnt[db.z], 1);
            int p7 = atomicAdd(&cnt[db.w], 1);
            if (p0 < CAP) csr16[da.x * CAP + p0] = (ushort_t)sa.x;
            if (p1 < CAP) csr16[da.y * CAP + p1] = (ushort_t)sa.y;
            if (p2 < CAP) csr16[da.z * CAP + p2] = (ushort_t)sa.z;
            if (p3 < CAP) csr16[da.w * CAP + p3] = (ushort_t)sa.w;
            if (p4 < CAP) csr16[db.x * CAP + p4] = (ushort_t)sb.x;
            if (p5 < CAP) csr16[db.y * CAP + p5] = (ushort_t)sb.y;
            if (p6 < CAP) csr16[db.z * CAP + p6] = (ushort_t)sb.z;
            if (p7 < CAP) csr16[db.w * CAP + p7] = (ushort_t)sb.w;
        } else {
            for (int i = base; i < N_EDGES; i++) {
                int d = dst[i];
                int slot = atomicAdd(&cnt[d], 1);
                if (slot < CAP) csr16[d * CAP + slot] = (ushort_t)src[i];
            }
        }
    } else if (b == 391) {
        int g = t;
        if (g <= NGRAPH) {
            int lo = 0, hi = N_NODES;
            while (lo < hi) {
                int mid = (lo + hi) >> 1;
                if (batch[mid] < g) lo = mid + 1; else hi = mid;
            }
            bound[g] = lo;
        }
        __syncthreads();
        if (g < NGRAPH) counts[g] = bound[g + 1] - bound[g];
    } else {
        int gid = (b - 392) * 256 + t;          // 192*256 = 49152 items
        int l = gid / (32 * 512);
        int rem = gid - l * 32 * 512;
        int tile = rem >> 9;
        int p = rem & 511;
        int lane = p >> 3, j = p & 7;
        int kk = tile >> 3, c = tile & 7;
        int k = 32 * kk + (lane >> 4) * 8 + j;
        int n = 16 * c + (lane & 15);
        const float* W = (l == 0) ? W0 : (l == 1) ? W1 : W2;
        float x = W[k * 128 + n];
        ushort_t hi = f2bf(x);
        ushort_t lo = f2bf(x - bf2f(hi));
        Whi[l * 16384 + rem] = hi;
        Wlo[l * 16384 + rem] = lo;
    }
}

// ---- convert x -> fp16 rows, pre-scaled by 1/sqrt(deg+1) ----
__global__ void k_cvt(const float* __restrict__ x, const int* __restrict__ cnt,
                      _Float16* __restrict__ X16) {
    int gid = blockIdx.x * 256 + threadIdx.x;     // 50000*16 = 800000 exact
    int i = gid >> 4, seg = gid & 15;             // seg: 8-feature octet
    float isd = rsqrtf((float)cnt[i] + 1.0f);
    const f32x4* px = (const f32x4*)(x + (size_t)i * HID + seg * 8);
    f32x4 a = px[0], b = px[1];
    f16x8 o;
    o[0] = (_Float16)(isd * a.x); o[1] = (_Float16)(isd * a.y);
    o[2] = (_Float16)(isd * a.z); o[3] = (_Float16)(isd * a.w);
    o[4] = (_Float16)(isd * b.x); o[5] = (_Float16)(isd * b.y);
    o[6] = (_Float16)(isd * b.z); o[7] = (_Float16)(isd * b.w);
    *(f16x8*)(X16 + (size_t)i * HID + seg * 8) = o;
}

// ---------------- fused layer: round-5-verified gather control flow ---------------
// Table = fp16 of isd_j * h_j. Wave wv: nodes blk*16+wv*4+r.
// Lane split: hl = lane&31 -> 4-feature group (8B); q = lane>>5 -> edge parity.
// 16-edge main tier (8 independent gathers in flight); 8-edge tier verbatim r5.
__global__ void k_layer(const _Float16* __restrict__ In,
                        const ushort_t* __restrict__ csr16, const int* __restrict__ cnt,
                        const ushort_t* __restrict__ Whi, const ushort_t* __restrict__ Wlo,
                        const float* __restrict__ bias, int scale_out,
                        int pool, const int* __restrict__ batch,
                        float* sums, float* maxs, _Float16* __restrict__ Out) {
    __shared__ float T[16][132];
    __shared__ int sg[16];
    int t = threadIdx.x, wv = t >> 6, lane = t & 63;
    int hl = lane & 31, q = lane >> 5;   // half-lane, half-index
    if (pool && t < 16) sg[t] = batch[blockIdx.x * 16 + t];

    // ---- gather phase: wave wv aggregates nodes (block*16 + wv*4 + r)
    for (int r = 0; r < 4; r++) {
        int i = blockIdx.x * 16 + wv * 4 + r;      // 3125*16 = 50000 exact
        int ci = cnt[i];
        int m = min(ci, CAP);
        float isdi = rsqrtf((float)ci + 1.0f);
        // preload full index row: int k holds edges 2k (lo16), 2k+1 (hi16)
        int packed = ((const int*)(csr16 + (size_t)i * CAP))[hl];
        float4 a0 = make_float4(0.f, 0.f, 0.f, 0.f);
        float4 a1 = a0, a2 = a0, a3 = a0;
        if (q == 0) {
            f16x4 sv = *(const f16x4*)(In + (size_t)i * HID + hl * 4);
            add4h(a0, sv);                         // self term (pre-scaled table)
        }
        int e = 0;
        for (; e + 15 < m; e += 16) {              // 8 gathers in flight per lane
            int k0 = e >> 1;
            int p0 = __shfl(packed, k0);
            int p1 = __shfl(packed, k0 + 1);
            int p2 = __shfl(packed, k0 + 2);
            int p3 = __shfl(packed, k0 + 3);
            int p4 = __shfl(packed, k0 + 4);
            int p5 = __shfl(packed, k0 + 5);
            int p6 = __shfl(packed, k0 + 6);
            int p7 = __shfl(packed, k0 + 7);
            int s0 = q ? exhi(p0) : exlo(p0);
            int s1 = q ? exhi(p1) : exlo(p1);
            int s2 = q ? exhi(p2) : exlo(p2);
            int s3 = q ? exhi(p3) : exlo(p3);
            int s4 = q ? exhi(p4) : exlo(p4);
            int s5 = q ? exhi(p5) : exlo(p5);
            int s6 = q ? exhi(p6) : exlo(p6);
            int s7 = q ? exhi(p7) : exlo(p7);
            f16x4 v0 = *(const f16x4*)(In + (size_t)s0 * HID + hl * 4);
            f16x4 v1 = *(const f16x4*)(In + (size_t)s1 * HID + hl * 4);
            f16x4 v2 = *(const f16x4*)(In + (size_t)s2 * HID + hl * 4);
            f16x4 v3 = *(const f16x4*)(In + (size_t)s3 * HID + hl * 4);
            f16x4 v4 = *(const f16x4*)(In + (size_t)s4 * HID + hl * 4);
            f16x4 v5 = *(const f16x4*)(In + (size_t)s5 * HID + hl * 4);
            f16x4 v6 = *(const f16x4*)(In + (size_t)s6 * HID + hl * 4);
            f16x4 v7 = *(const f16x4*)(In + (size_t)s7 * HID + hl * 4);
            add4h(a0, v0); add4h(a1, v1); add4h(a2, v2); add4h(a3, v3);
            add4h(a0, v4); add4h(a1, v5); add4h(a2, v6); add4h(a3, v7);
        }
        for (; e + 7 < m; e += 8) {                // round-5 body verbatim
            int k0 = e >> 1;
            int p0 = __shfl(packed, k0);
            int p1 = __shfl(packed, k0 + 1);
            int p2 = __shfl(packed, k0 + 2);
            int p3 = __shfl(packed, k0 + 3);
            int s0 = q ? exhi(p0) : exlo(p0);
            int s1 = q ? exhi(p1) : exlo(p1);
            int s2 = q ? exhi(p2) : exlo(p2);
            int s3 = q ? exhi(p3) : exlo(p3);
            f16x4 v0 = *(const f16x4*)(In + (size_t)s0 * HID + hl * 4);
            f16x4 v1 = *(const f16x4*)(In + (size_t)s1 * HID + hl * 4);
            f16x4 v2 = *(const f16x4*)(In + (size_t)s2 * HID + hl * 4);
            f16x4 v3 = *(const f16x4*)(In + (size_t)s3 * HID + hl * 4);
            add4h(a0, v0); add4h(a1, v1); add4h(a2, v2); add4h(a3, v3);
        }
        for (; e + 1 < m; e += 2) {
            int p = __shfl(packed, e >> 1);
            int s0 = q ? exhi(p) : exlo(p);
            f16x4 v0 = *(const f16x4*)(In + (size_t)s0 * HID + hl * 4);
            add4h(a0, v0);
        }
        if (e < m && q == 0) {
            int p = __shfl(packed, e >> 1);
            int s0 = exlo(p);
            f16x4 v0 = *(const f16x4*)(In + (size_t)s0 * HID + hl * 4);
            add4h(a0, v0);
        }
        float4 s4;
        s4.x = (a0.x + a1.x) + (a2.x + a3.x);
        s4.y = (a0.y + a1.y) + (a2.y + a3.y);
        s4.z = (a0.z + a1.z) + (a2.z + a3.z);
        s4.w = (a0.w + a1.w) + (a2.w + a3.w);
        // combine the two halves (lane ^ 32 partner holds the other parity's sum)
        s4.x += __shfl_xor(s4.x, 32);
        s4.y += __shfl_xor(s4.y, 32);
        s4.z += __shfl_xor(s4.z, 32);
        s4.w += __shfl_xor(s4.w, 32);
        if (q == 0) {
            float4 o;
            o.x = isdi * s4.x; o.y = isdi * s4.y;
            o.z = isdi * s4.z; o.w = isdi * s4.w;
            *(float4*)&T[wv * 4 + r][hl * 4] = o;
        }
    }
    __syncthreads();

    // ---- MFMA phase: wave wv -> cols [wv*32, wv*32+32)
    int mrow = lane & 15, qq = lane >> 4;
    f32x4 acc[2];
    acc[0] = (f32x4){0.f, 0.f, 0.f, 0.f};
    acc[1] = (f32x4){0.f, 0.f, 0.f, 0.f};
#pragma unroll
    for (int kk = 0; kk < 4; kk++) {
        const float* tp = &T[mrow][kk * 32 + qq * 8];
        float4 p0 = *(const float4*)tp;
        float4 p1 = *(const float4*)(tp + 4);
        float av[8] = {p0.x, p0.y, p0.z, p0.w, p1.x, p1.y, p1.z, p1.w};
        bf16x8 ahi, alo;
#pragma unroll
        for (int j = 0; j < 8; j++) {
            ushort_t hbits = f2bf(av[j]);
            ahi[j] = (short)hbits;
            alo[j] = (short)f2bf(av[j] - bf2f(hbits));
        }
#pragma unroll
        for (int cl = 0; cl < 2; cl++) {
            int c = wv * 2 + cl;
            const bf16x8 bhi = *(const bf16x8*)(Whi + (((kk * 8 + c) * 64 + lane) << 3));
            const bf16x8 blo = *(const bf16x8*)(Wlo + (((kk * 8 + c) * 64 + lane) << 3));
            acc[cl] = __builtin_amdgcn_mfma_f32_16x16x32_bf16(ahi, bhi, acc[cl], 0, 0, 0);
            acc[cl] = __builtin_amdgcn_mfma_f32_16x16x32_bf16(alo, bhi, acc[cl], 0, 0, 0);
            acc[cl] = __builtin_amdgcn_mfma_f32_16x16x32_bf16(ahi, blo, acc[cl], 0, 0, 0);
        }
    }
    // epilogue: C/D col = mrow, row = qq*4+rr
    int rb = blockIdx.x * 16 + qq * 4;
    if (!pool) {
        float osc[4];
#pragma unroll
        for (int rr = 0; rr < 4; rr++)
            osc[rr] = scale_out ? rsqrtf((float)cnt[rb + rr] + 1.0f) : 1.0f;
#pragma unroll
        for (int cl = 0; cl < 2; cl++) {
            int col = (wv * 2 + cl) * 16 + mrow;
            float bcol = bias[col];
#pragma unroll
            for (int rr = 0; rr < 4; rr++) {
                float val = fmaxf(acc[cl][rr] + bcol, 0.f);
                Out[(size_t)(rb + rr) * HID + col] = (_Float16)(val * osc[rr]);
            }
        }
    } else {
        // write relu'd values back into T (rows x feats), then block pool-reduce
        __syncthreads();   // all waves done reading T
#pragma unroll
        for (int cl = 0; cl < 2; cl++) {
            int col = (wv * 2 + cl) * 16 + mrow;
            float bcol = bias[col];
#pragma unroll
            for (int rr = 0; rr < 4; rr++)
                T[qq * 4 + rr][col] = fmaxf(acc[cl][rr] + bcol, 0.f);
        }
        __syncthreads();
        int f = t & 127, half = t >> 7;   // half 0: sums, half 1: maxs
        int cur = sg[0];
        float s = 0.f, mx = 0.f;
        for (int r = 0; r < 16; r++) {
            int g = sg[r];
            if (g != cur) {
                if (half == 0) atomicAdd(&sums[cur * HID + f], s);
                else atomicMax((int*)&maxs[cur * HID + f], __float_as_int(mx));
                s = 0.f; mx = 0.f; cur = g;
            }
            float v = T[r][f];
            s += v;
            mx = fmaxf(mx, v);
        }
        if (half == 0) atomicAdd(&sums[cur * HID + f], s);
        else atomicMax((int*)&maxs[cur * HID + f], __float_as_int(mx));
    }
}

// ---------------- head ----------------
__global__ void k_final(const float* __restrict__ sums, const float* __restrict__ maxs,
                        const int* __restrict__ counts, const float* __restrict__ Wa,
                        const float* __restrict__ ba, float* __restrict__ out) {
    __shared__ float a[256];
    __shared__ float red[4];
    int g = blockIdx.x, t = threadIdx.x;
    float denom = fmaxf((float)counts[g], 1.f);
    float val = (t < 128) ? (sums[g * HID + t] / denom) : maxs[g * HID + (t - 128)];
    a[t] = val;
    out[NGRAPH * NCLS + g * 256 + t] = val;
    __syncthreads();
    for (int c = 0; c < NCLS; c++) {
        float p = a[t] * Wa[t * NCLS + c];
        for (int o = 32; o > 0; o >>= 1) p += __shfl_down(p, o);
        if ((t & 63) == 0) red[t >> 6] = p;
        __syncthreads();
        if (t == 0) {
            out[g * NCLS + c] = red[0] + red[1] + red[2] + red[3] + ba[c];
        }
        __syncthreads();
    }
}

extern "C" void kernel_launch(void* const* d_in, const int* in_sizes, int n_in,
                              void* d_out, int out_size, void* d_ws, size_t ws_size,
                              hipStream_t stream) {
    const float* x = (const float*)d_in[0];
    const int* ei = (const int*)d_in[1];
    const int* src = ei;
    const int* dst = ei + N_EDGES;
    const int* batch = (const int*)d_in[2];
    const float* W0 = (const float*)d_in[3];
    const float* b0 = (const float*)d_in[4];
    const float* W1 = (const float*)d_in[5];
    const float* b1 = (const float*)d_in[6];
    const float* W2 = (const float*)d_in[7];
    const float* b2 = (const float*)d_in[8];
    const float* Wa = (const float*)d_in[9];
    const float* ba = (const float*)d_in[10];
    float* out = (float*)d_out;

    char* ws = (char*)d_ws;
    int*       cnt    = (int*)(ws + 0);             // 50000 i32
    int*       bound  = (int*)(ws + 200192);        // 65 i32
    int*       counts = (int*)(ws + 200576);        // 64 i32
    float*     sums   = (float*)(ws + 200832);      // 8192 f32
    float*     maxs   = (float*)(ws + 233600);      // 8192 f32
    ushort_t*  Whi    = (ushort_t*)(ws + 266368);   // 3*16384 bf16
    ushort_t*  Wlo    = (ushort_t*)(ws + 364672);   // 3*16384 bf16
    ushort_t*  csr16  = (ushort_t*)(ws + 462976);   // 50000*64 u16 (6.4 MB)
    _Float16*  X16    = (_Float16*)(ws + 7462976);  // 50000x128 f16 (12.8 MB)
    _Float16*  hA     = (_Float16*)(ws + 20262976); // 50000x128 f16
    _Float16*  hB     = (_Float16*)(ws + 33062976); // 50000x128 f16
    // total 45,862,976 B

    // zero cnt/bound/counts/sums/maxs in one capture-safe memset
    hipMemsetAsync(ws, 0, 266368, stream);
    k_prep<<<584, 256, 0, stream>>>(src, dst, cnt, csr16, batch, bound, counts,
                                    W0, W1, W2, Whi, Wlo);
    k_cvt<<<3125, 256, 0, stream>>>(x, cnt, X16);

    // fused layers, fp16 gather tables (pre-scaled); layer 3 pools in-kernel
    k_layer<<<3125, 256, 0, stream>>>(X16, csr16, cnt, Whi, Wlo, b0, 1,
                                      0, batch, sums, maxs, hA);
    k_layer<<<3125, 256, 0, stream>>>(hA, csr16, cnt, Whi + 16384, Wlo + 16384, b1, 1,
                                      0, batch, sums, maxs, hB);
    k_layer<<<3125, 256, 0, stream>>>(hB, csr16, cnt, Whi + 32768, Wlo + 32768, b2, 0,
                                      1, batch, sums, maxs, hA);

    k_final<<<NGRAPH, 256, 0, stream>>>(sums, maxs, counts, Wa, ba, out);
}